// Round 10
// baseline (999.079 us; speedup 1.0000x reference)
//
#include <hip/hip_runtime.h>
#include <hip/hip_bf16.h>

#define TK 4096   // tokens
#define DD 2048   // hidden
#define FF 4096   // intermediate
#define NE 8      // experts
#define BM 128
#define BN 128
#define BN2 256   // gemm2 N-tile
#define BKR 32    // reg-staged fallback K-tile
#define BKP 64    // pipelined K-tile

typedef __attribute__((ext_vector_type(8))) short bf16x8;
typedef __attribute__((ext_vector_type(4))) short bf16x4;
typedef __attribute__((ext_vector_type(4))) float f32x4;

__device__ __forceinline__ unsigned short f2bf(float f) {
  return __builtin_bit_cast(unsigned short, __float2bfloat16(f));  // v_cvt_pk_bf16_f32
}
__device__ __forceinline__ float bf2f(unsigned short u) {
  return __builtin_bit_cast(float, (unsigned)u << 16);
}

// async global->LDS, 16B per lane. LDS dest is wave-uniform base + lane*16.
__device__ __forceinline__ void gl16(const unsigned short* g, unsigned short* l) {
  __builtin_amdgcn_global_load_lds(
      (const __attribute__((address_space(1))) unsigned int*)g,
      (__attribute__((address_space(3))) unsigned int*)l, 16, 0, 0);
}

#define VMCNT(n) asm volatile("s_waitcnt vmcnt(" #n ")" ::: "memory")
#define SBAR()   __builtin_amdgcn_s_barrier()
#define MFMA_(a, b, c) __builtin_amdgcn_mfma_f32_16x16x32_bf16(a, b, c, 0, 0, 0)

// ---- fallback-path swizzle helpers ----
__device__ __forceinline__ int g_swz(int row) { return ((row >> 1) & 3) ^ ((row >> 3) & 3); }
__device__ __forceinline__ int swzoff(int row, int bir) {
  return row * 64 + ((((bir >> 4) ^ g_swz(row)) & 3) << 4) + (bir & 15);
}
__device__ __forceinline__ int permB(int f) {
  return (f & 0x60) | ((f & 3) << 3) | ((f >> 2) & 7);
}

// ---------------- router: 1 wave per token (emits X bf16 + token->slot map) ----------------
__global__ void k_router(const float* __restrict__ x, const float* __restrict__ gw,
                         int* __restrict__ cnt, int* __restrict__ ltok,
                         float* __restrict__ lw, unsigned short* __restrict__ xb,
                         int2* __restrict__ t2s) {
  int tok = (blockIdx.x * blockDim.x + threadIdx.x) >> 6;
  int lane = threadIdx.x & 63;
  if (tok >= TK) return;
  const float* xr = x + (size_t)tok * DD;
  float a0=0,a1=0,a2=0,a3=0,a4=0,a5=0,a6=0,a7=0;
  for (int p = 0; p < DD / 256; ++p) {
    int d0 = p * 256 + lane * 4;
    f32x4 xv = *(const f32x4*)(xr + d0);
    if (xb) {
      bf16x4 t;
      t[0] = (short)f2bf(xv[0]); t[1] = (short)f2bf(xv[1]);
      t[2] = (short)f2bf(xv[2]); t[3] = (short)f2bf(xv[3]);
      *(bf16x4*)(xb + (size_t)tok * DD + d0) = t;
    }
#pragma unroll
    for (int j = 0; j < 4; ++j) {
      float xs = xv[j];
      const f32x4* g = (const f32x4*)(gw + (size_t)(d0 + j) * NE);
      f32x4 g0 = g[0], g1 = g[1];
      a0 += xs * g0[0]; a1 += xs * g0[1]; a2 += xs * g0[2]; a3 += xs * g0[3];
      a4 += xs * g1[0]; a5 += xs * g1[1]; a6 += xs * g1[2]; a7 += xs * g1[3];
    }
  }
#pragma unroll
  for (int s = 32; s > 0; s >>= 1) {
    a0 += __shfl_xor(a0, s, 64); a1 += __shfl_xor(a1, s, 64);
    a2 += __shfl_xor(a2, s, 64); a3 += __shfl_xor(a3, s, 64);
    a4 += __shfl_xor(a4, s, 64); a5 += __shfl_xor(a5, s, 64);
    a6 += __shfl_xor(a6, s, 64); a7 += __shfl_xor(a7, s, 64);
  }
  if (lane == 0) {
    float p_[NE] = {a0, a1, a2, a3, a4, a5, a6, a7};
    float m = p_[0];
#pragma unroll
    for (int e = 1; e < NE; ++e) m = fmaxf(m, p_[e]);
    float ssum = 0.f;
#pragma unroll
    for (int e = 0; e < NE; ++e) { p_[e] = __expf(p_[e] - m); ssum += p_[e]; }
    float inv = 1.f / ssum;
    int i1 = 0; float b1 = p_[0];
#pragma unroll
    for (int e = 1; e < NE; ++e) if (p_[e] > b1) { b1 = p_[e]; i1 = e; }
    int i2 = -1; float b2 = -1.f;
#pragma unroll
    for (int e = 0; e < NE; ++e) if (e != i1 && p_[e] > b2) { b2 = p_[e]; i2 = e; }
    int s1 = atomicAdd(&cnt[i1], 1);
    ltok[i1 * TK + s1] = tok; lw[i1 * TK + s1] = b1 * inv;
    int s2 = atomicAdd(&cnt[i2], 1);
    ltok[i2 * TK + s2] = tok; lw[i2 * TK + s2] = b2 * inv;
    if (t2s) t2s[tok] = make_int2(i1 * TK + s1, i2 * TK + s2);
  }
}

__global__ void k_prefix(const int* __restrict__ cnt, int* __restrict__ off) {
  if (threadIdx.x == 0) {
    int a = 0;
#pragma unroll
    for (int e = 0; e < NE; ++e) { off[e] = a; a += cnt[e]; }
    off[NE] = a;
  }
}

// ------- transpose+convert, pure-register: fp32 [R][C] -> bf16 [C'][R] -------
// mode 0: identity rows. mode 1/2: 16-col interleave into a [2C][R] buffer:
// output row r' = ((f>>4)<<5) + (mode-1)*16 + (f&15)  (W1 rows / W3 rows paired).
__global__ __launch_bounds__(256)
void k_tr(const float* __restrict__ src0, unsigned short* __restrict__ dst0,
          int R, int C, int mode) {
  const int e = blockIdx.z;
  const float* src = src0 + (size_t)e * R * C;
  unsigned short* dst = dst0 + (size_t)e * R * C * (mode ? 2 : 1);
  const int tid = threadIdx.x;
  const int w = tid >> 6, lane = tid & 63;
  const int r0 = blockIdx.y * 256 + w * 64 + (lane >> 3) * 8;
  const int c0 = blockIdx.x * 32 + (lane & 7) * 4;
  f32x4 v[8];
#pragma unroll
  for (int j = 0; j < 8; ++j) v[j] = *(const f32x4*)(src + (size_t)(r0 + j) * C + c0);
#pragma unroll
  for (int jc = 0; jc < 4; ++jc) {
    bf16x8 o;
#pragma unroll
    for (int j = 0; j < 8; ++j) o[j] = (short)f2bf(v[j][jc]);
    int f = c0 + jc;
    int rr = mode ? (((f >> 4) << 5) + ((mode - 1) << 4) + (f & 15)) : f;
    *(bf16x8*)(dst + (size_t)rr * R + r0) = o;
  }
}

// ---------------- combine: out[t] = O[slot1(t)] + O[slot2(t)] ----------------
__global__ __launch_bounds__(256)
void k_comb(const unsigned short* __restrict__ O, const int2* __restrict__ t2s,
            const int* __restrict__ off, float* __restrict__ out) {
  const int idx = blockIdx.x * 256 + threadIdx.x;
  const int t = idx >> 8;
  const int d0 = (idx & 255) * 8;
  const int2 v = t2s[t];
  const int s1 = off[v.x >> 12] + (v.x & (TK - 1));
  const int s2 = off[v.y >> 12] + (v.y & (TK - 1));
  bf16x8 a = *(const bf16x8*)(O + (size_t)s1 * DD + d0);
  bf16x8 b = *(const bf16x8*)(O + (size_t)s2 * DD + d0);
  f32x4 r0, r1;
#pragma unroll
  for (int j = 0; j < 4; ++j) {
    r0[j] = bf2f((unsigned short)a[j]) + bf2f((unsigned short)b[j]);
    r1[j] = bf2f((unsigned short)a[j + 4]) + bf2f((unsigned short)b[j + 4]);
  }
  float* o = out + (size_t)t * DD + d0;
  *(f32x4*)o = r0;
  *(f32x4*)(o + 4) = r1;
}

// ============ GEMM1, 8-phase 256x256 template (T3+T4+T5) ============
// B = w13t (W1/W3 16-col-interleaved, [2F][D]) -> single-operand GEMM; the wave's
// frag pairs (n=0,1) and (n=2,3) hold (s1,s3) for identical F columns.
// 512 thr = 8 waves (2M x 4N); per-wave out 128x64 -> acc[8][4].
// LDS 128 KB: A/B x dbuf x 2 K-halves (256 rows x 32 K, 64B rows, swizzle
// chunk c^=(r>>1)&3 on source + read; staging linear -> conflict-free).
// Phases per K-tile: P1 kk0·n01, P2 kk0·n23, P3 kk1·n01, P4 kk1·n23; each
// stages ONE half-tile of tile t+1 (order A0,B0,A1,B1) into buf^1; 16 MFMA in
// setprio(1); 2 barriers/phase; counted VMCNT(4) ONLY at P2/P4 ends (ledger:
// exactly the last two stage-calls in flight; gated halves staged 2-3 phases
// earlier). Last iter stages in-bounds garbage to keep the ledger uniform.
__global__ __launch_bounds__(512, 2)
void k_gemm1p(const unsigned short* __restrict__ xb, const unsigned short* __restrict__ w13t,
              const int* __restrict__ cnt, const int* __restrict__ off,
              const int* __restrict__ ltok, const float* __restrict__ lw,
              unsigned short* __restrict__ H) {
  const int e = blockIdx.z;
  const int ce = cnt[e];
  const int m0 = blockIdx.y * 256;
  if (m0 >= ce) return;
  const int n0 = blockIdx.x * 256;          // column in the 2F interleaved space
  const int tid = threadIdx.x, lane = tid & 63, w = tid >> 6;
  const int wm = w >> 2, wn = w & 3;
  const unsigned short* W = w13t + (size_t)e * 2 * FF * DD;
  const int base = off[e];

  __shared__ __align__(16) unsigned short As[2][2][256 * 32];  // [buf][Kh] 16KB
  __shared__ __align__(16) unsigned short Bs[2][2][256 * 32];

  // staging: K-half = 256 rows x 32 cols; call i covers rows i*128+w*16+(lane>>2),
  // lane&3 = phys chunk; source chunk pre-swizzled = (lane&3)^((lane>>3)&3).
  const int presw = ((lane & 3) ^ ((lane >> 3) & 3)) * 8;
  const unsigned short *aSrc[2], *bSrc[2];
#pragma unroll
  for (int i = 0; i < 2; ++i) {
    int row = i * 128 + w * 16 + (lane >> 2);
    int gm = m0 + row;
    int tok = (gm < ce) ? ltok[e * TK + gm] : ltok[e * TK];  // clamp; masked at store
    aSrc[i] = xb + (size_t)tok * DD + presw;
    bSrc[i] = W + (size_t)(n0 + row) * DD + presw;
  }
  const int ldsrow = (w * 16) * 32;  // call i adds i*128*32

  // frag-read byte offsets within one 16KB K-half region
  const int c = lane >> 4;
  int aOff[8], bOff[4];
#pragma unroll
  for (int m = 0; m < 8; ++m) {
    int r = wm * 128 + m * 16 + (lane & 15);
    aOff[m] = r * 64 + ((c ^ ((r >> 1) & 3)) << 4);
  }
#pragma unroll
  for (int n = 0; n < 4; ++n) {
    int r = wn * 64 + n * 16 + (lane & 15);
    bOff[n] = r * 64 + ((c ^ ((r >> 1) & 3)) << 4);
  }

  f32x4 acc[8][4];
#pragma unroll
  for (int m = 0; m < 8; ++m)
#pragma unroll
    for (int n = 0; n < 4; ++n)
#pragma unroll
      for (int j = 0; j < 4; ++j) acc[m][n][j] = 0.f;

  auto SA = [&](int buf, int kh) {
#pragma unroll
    for (int i = 0; i < 2; ++i)
      gl16(aSrc[i] + kh * 32, &As[buf][kh][ldsrow + i * 128 * 32]);
  };
  auto SB = [&](int buf, int kh) {
#pragma unroll
    for (int i = 0; i < 2; ++i)
      gl16(bSrc[i] + kh * 32, &Bs[buf][kh][ldsrow + i * 128 * 32]);
  };

  // prologue: tile 0 into buf0; gate A0,B0 (leave A1,B1 in flight)
  SA(0, 0); SB(0, 0); SA(0, 1); SB(0, 1);
  aSrc[0] += BKP; aSrc[1] += BKP; bSrc[0] += BKP; bSrc[1] += BKP;
  VMCNT(4);
  SBAR();

  const int NT = DD / BKP;  // 32
  int buf = 0;
  bf16x8 afr[8], bfA, bfB;
  for (int kt = 0; kt < NT; ++kt) {
    const char* A0 = (const char*)As[buf][0];
    const char* A1 = (const char*)As[buf][1];
    const char* B0 = (const char*)Bs[buf][0];
    const char* B1 = (const char*)Bs[buf][1];
    // ---- P1: kk0, n0-1; stage A.Kh0(t+1)
#pragma unroll
    for (int m = 0; m < 8; ++m) afr[m] = *(const bf16x8*)(A0 + aOff[m]);
    bfA = *(const bf16x8*)(B0 + bOff[0]);
    bfB = *(const bf16x8*)(B0 + bOff[1]);
    SA(buf ^ 1, 0);
    __builtin_amdgcn_s_setprio(1);
#pragma unroll
    for (int m = 0; m < 8; ++m) {
      acc[m][0] = MFMA_(afr[m], bfA, acc[m][0]);
      acc[m][1] = MFMA_(afr[m], bfB, acc[m][1]);
    }
    __builtin_amdgcn_s_setprio(0);
    SBAR();
    // ---- P2: kk0, n2-3; stage B.Kh0(t+1); gate Kh1(t)
    bfA = *(const bf16x8*)(B0 + bOff[2]);
    bfB = *(const bf16x8*)(B0 + bOff[3]);
    SB(buf ^ 1, 0);
    __builtin_amdgcn_s_setprio(1);
#pragma unroll
    for (int m = 0; m < 8; ++m) {
      acc[m][2] = MFMA_(afr[m], bfA, acc[m][2]);
      acc[m][3] = MFMA_(afr[m], bfB, acc[m][3]);
    }
    __builtin_amdgcn_s_setprio(0);
    VMCNT(4);
    SBAR();
    // ---- P3: kk1, n0-1; stage A.Kh1(t+1)
#pragma unroll
    for (int m = 0; m < 8; ++m) afr[m] = *(const bf16x8*)(A1 + aOff[m]);
    bfA = *(const bf16x8*)(B1 + bOff[0]);
    bfB = *(const bf16x8*)(B1 + bOff[1]);
    SA(buf ^ 1, 1);
    __builtin_amdgcn_s_setprio(1);
#pragma unroll
    for (int m = 0; m < 8; ++m) {
      acc[m][0] = MFMA_(afr[m], bfA, acc[m][0]);
      acc[m][1] = MFMA_(afr[m], bfB, acc[m][1]);
    }
    __builtin_amdgcn_s_setprio(0);
    SBAR();
    // ---- P4: kk1, n2-3; stage B.Kh1(t+1); gate Kh0(t+1)
    bfA = *(const bf16x8*)(B1 + bOff[2]);
    bfB = *(const bf16x8*)(B1 + bOff[3]);
    SB(buf ^ 1, 1);
    __builtin_amdgcn_s_setprio(1);
#pragma unroll
    for (int m = 0; m < 8; ++m) {
      acc[m][2] = MFMA_(afr[m], bfA, acc[m][2]);
      acc[m][3] = MFMA_(afr[m], bfB, acc[m][3]);
    }
    __builtin_amdgcn_s_setprio(0);
    VMCNT(4);
    SBAR();
    aSrc[0] += BKP; aSrc[1] += BKP; bSrc[0] += BKP; bSrc[1] += BKP;
    buf ^= 1;
  }

  // epilogue: frag pairs (2p, 2p+1) = (s1, s3) for F-col fbase + p*16 + l
#pragma unroll
  for (int m = 0; m < 8; ++m) {
    const int rl = wm * 128 + m * 16 + ((lane >> 4) << 2);
#pragma unroll
    for (int p = 0; p < 2; ++p) {
      const int fcol = ((n0 + wn * 64) >> 1) + p * 16 + (lane & 15);
#pragma unroll
      for (int j = 0; j < 4; ++j) {
        int r = m0 + rl + j;
        if (r < ce) {
          float s1 = acc[m][2 * p][j], s3 = acc[m][2 * p + 1][j];
          float h = s1 / (1.f + __expf(-s1)) * s3 * lw[e * TK + r];
          H[(size_t)(base + r) * FF + fcol] = f2bf(h);
        }
      }
    }
  }
}

// ---------------- GEMM2: O[slot] = H W2t (bf16 slot-output, no atomics) ----------------
__global__ __launch_bounds__(256, 2)
void k_gemm2g(const unsigned short* __restrict__ H, const unsigned short* __restrict__ w2t,
              const int* __restrict__ cnt, const int* __restrict__ off,
              unsigned short* __restrict__ O) {
  const int e = blockIdx.z;
  const int ce = cnt[e];
  const int m0 = blockIdx.y * BM;
  if (m0 >= ce) return;
  const int n0 = blockIdx.x * BN2;
  const int tid = threadIdx.x, lane = tid & 63, w = tid >> 6;
  const int wr = w >> 1, wc = w & 1;
  const unsigned short* W2 = w2t + (size_t)e * DD * FF;  // [D][F]
  const int base = off[e];

  __shared__ __align__(16) unsigned short As[BM * BKP];
  __shared__ __align__(16) unsigned short Bs[2][BN2 * BKP];

  const int swz8 = ((lane & 7) ^ ((lane >> 3) & 7)) * 8;
  const unsigned short *aSrc[4], *bSrc[8];
#pragma unroll
  for (int i = 0; i < 4; ++i) {
    int row = w * 32 + i * 8 + (lane >> 3);
    int gm = m0 + row;
    int hr = (gm < ce) ? gm : 0;
    aSrc[i] = H + (size_t)(base + hr) * FF + swz8;
  }
#pragma unroll
  for (int i = 0; i < 8; ++i) {
    int row = w * 64 + i * 8 + (lane >> 3);
    bSrc[i] = W2 + (size_t)(n0 + row) * FF + swz8;
  }

  const int kc = lane >> 4;
  int aOff[4][2], bOff[8][2];
#pragma unroll
  for (int m = 0; m < 4; ++m) {
    int row = wr * 64 + m * 16 + (lane & 15);
#pragma unroll
    for (int kk = 0; kk < 2; ++kk) {
      int cc = kk * 4 + kc;
      aOff[m][kk] = row * 128 + ((cc ^ (row & 7)) << 4);
    }
  }
#pragma unroll
  for (int n = 0; n < 8; ++n) {
    int row = wc * 128 + n * 16 + (lane & 15);
#pragma unroll
    for (int kk = 0; kk < 2; ++kk) {
      int cc = kk * 4 + kc;
      bOff[n][kk] = row * 128 + ((cc ^ (row & 7)) << 4);
    }
  }

  f32x4 acc[4][8];
#pragma unroll
  for (int m = 0; m < 4; ++m)
#pragma unroll
    for (int n = 0; n < 8; ++n)
#pragma unroll
      for (int j = 0; j < 4; ++j) acc[m][n][j] = 0.f;

  auto STAGE_A = [&]() {
#pragma unroll
    for (int i = 0; i < 4; ++i) {
      gl16(aSrc[i], &As[(w * 4 + i) * 512]);
      aSrc[i] += BKP;
    }
  };
  auto STAGE_B = [&](int buf) {
#pragma unroll
    for (int i = 0; i < 8; ++i) {
      gl16(bSrc[i], &Bs[buf][(w * 8 + i) * 512]);
      bSrc[i] += BKP;
    }
  };
  auto COMPUTE = [&](int buf) {
#pragma unroll
    for (int kk = 0; kk < 2; ++kk) {
      bf16x8 af[4];
#pragma unroll
      for (int m = 0; m < 4; ++m) af[m] = *(const bf16x8*)((const char*)As + aOff[m][kk]);
#pragma unroll
      for (int n = 0; n < 8; ++n) {
        bf16x8 bf = *(const bf16x8*)((const char*)Bs[buf] + bOff[n][kk]);
#pragma unroll
        for (int m = 0; m < 4; ++m)
          acc[m][n] = __builtin_amdgcn_mfma_f32_16x16x32_bf16(af[m], bf, acc[m][n], 0, 0, 0);
      }
    }
  };

  const int NT = FF / BKP;
  STAGE_A();
  STAGE_B(0);
  int b = 0;
  for (int kt = 0; kt < NT - 1; ++kt) {
    STAGE_B(b ^ 1);
    VMCNT(8);
    SBAR();
    COMPUTE(b);
    SBAR();
    STAGE_A();
    b ^= 1;
  }
  VMCNT(0);
  SBAR();
  COMPUTE(b);

#pragma unroll
  for (int m = 0; m < 4; ++m) {
    const int rbase = wr * 64 + m * 16 + ((lane >> 4) << 2);
#pragma unroll
    for (int n = 0; n < 8; ++n) {
      const int col = n0 + wc * 128 + n * 16 + (lane & 15);
#pragma unroll
      for (int j = 0; j < 4; ++j) {
        int r = m0 + rbase + j;
        if (r < ce) O[(size_t)(base + r) * DD + col] = f2bf(acc[m][n][j]);
      }
    }
  }
}

// ================== fallback reg-staged GEMMs (used only if ws too small) ==================
__global__ __launch_bounds__(256, 2)
void k_gemm1(const float* __restrict__ x, const float* __restrict__ w1g,
             const float* __restrict__ w3g, const int* __restrict__ cnt,
             const int* __restrict__ off, const int* __restrict__ ltok,
             const float* __restrict__ lw, unsigned short* __restrict__ H) {
  const int e = blockIdx.z;
  const int ce = cnt[e];
  const int m0 = blockIdx.y * BM;
  if (m0 >= ce) return;
  const int n0 = blockIdx.x * BN;
  const int tid = threadIdx.x, lane = tid & 63, wv = tid >> 6;
  const int wr = wv >> 1, wc = wv & 1;
  const float* W1 = w1g + (size_t)e * DD * FF;
  const float* W3 = w3g + (size_t)e * DD * FF;
  const int base = off[e];

  __shared__ unsigned short As[2][BM * BKR];
  __shared__ unsigned short B1s[2][BN * BKR];
  __shared__ unsigned short B3s[2][BN * BKR];

  const int arow = tid >> 1, ah = tid & 1;
  const float* xrow = (m0 + arow < ce) ? (x + (size_t)ltok[e * TK + (m0 + arow)] * DD) : nullptr;
  const int dblk = tid >> 5, fblk = tid & 31;

  const int kb = (lane >> 4) * 16;
  int aOff[4], bOff[4], wAoff[4], wBoff[4];
#pragma unroll
  for (int m = 0; m < 4; ++m) aOff[m] = swzoff(wr * 64 + m * 16 + (lane & 15), kb);
#pragma unroll
  for (int n = 0; n < 4; ++n) bOff[n] = swzoff(permB(wc * 64 + n * 16 + (lane & 15)), kb);
#pragma unroll
  for (int j = 0; j < 4; ++j) {
    wAoff[j] = swzoff(arow, ah * 32 + j * 8);
    wBoff[j] = swzoff(permB(fblk * 4 + j), dblk * 8);
  }

  f32x4 acc1[4][4], acc3[4][4];
#pragma unroll
  for (int m = 0; m < 4; ++m)
#pragma unroll
    for (int n = 0; n < 4; ++n)
#pragma unroll
      for (int j = 0; j < 4; ++j) { acc1[m][n][j] = 0.f; acc3[m][n][j] = 0.f; }

  f32x4 av[4], v1[4], v3[4];

  auto LOAD = [&](int kt) {
    const int k0 = kt * BKR;
#pragma unroll
    for (int j = 0; j < 4; ++j) {
      if (xrow) av[j] = *(const f32x4*)(xrow + k0 + ah * 16 + j * 4);
      else { av[j][0] = 0.f; av[j][1] = 0.f; av[j][2] = 0.f; av[j][3] = 0.f; }
    }
    const float* p1 = W1 + (size_t)(k0 + dblk * 4) * FF + (n0 + fblk * 4);
    const float* p3 = W3 + (size_t)(k0 + dblk * 4) * FF + (n0 + fblk * 4);
#pragma unroll
    for (int r = 0; r < 4; ++r) {
      v1[r] = *(const f32x4*)(p1 + (size_t)r * FF);
      v3[r] = *(const f32x4*)(p3 + (size_t)r * FF);
    }
  };
  auto STORE = [&](int buf) {
#pragma unroll
    for (int j = 0; j < 4; ++j) {
      bf16x4 t;
      t[0] = (short)f2bf(av[j][0]); t[1] = (short)f2bf(av[j][1]);
      t[2] = (short)f2bf(av[j][2]); t[3] = (short)f2bf(av[j][3]);
      *(bf16x4*)((char*)As[buf] + wAoff[j]) = t;
    }
#pragma unroll
    for (int j = 0; j < 4; ++j) {
      bf16x4 t1, t3;
      t1[0] = (short)f2bf(v1[0][j]); t1[1] = (short)f2bf(v1[1][j]);
      t1[2] = (short)f2bf(v1[2][j]); t1[3] = (short)f2bf(v1[3][j]);
      t3[0] = (short)f2bf(v3[0][j]); t3[1] = (short)f2bf(v3[1][j]);
      t3[2] = (short)f2bf(v3[2][j]); t3[3] = (short)f2bf(v3[3][j]);
      *(bf16x4*)((char*)B1s[buf] + wBoff[j]) = t1;
      *(bf16x4*)((char*)B3s[buf] + wBoff[j]) = t3;
    }
  };

  LOAD(0); STORE(0);
  int cur = 0;
  const int NT = DD / BKR;
  for (int kt = 0; kt < NT; ++kt) {
    if (kt + 1 < NT) LOAD(kt + 1);
    __syncthreads();
    bf16x8 af[4];
#pragma unroll
    for (int m = 0; m < 4; ++m) af[m] = *(const bf16x8*)((const char*)As[cur] + aOff[m]);
#pragma unroll
    for (int n = 0; n < 4; ++n) {
      bf16x8 b1 = *(const bf16x8*)((const char*)B1s[cur] + bOff[n]);
      bf16x8 b3 = *(const bf16x8*)((const char*)B3s[cur] + bOff[n]);
#pragma unroll
      for (int m = 0; m < 4; ++m) {
        acc1[m][n] = __builtin_amdgcn_mfma_f32_16x16x32_bf16(af[m], b1, acc1[m][n], 0, 0, 0);
        acc3[m][n] = __builtin_amdgcn_mfma_f32_16x16x32_bf16(af[m], b3, acc3[m][n], 0, 0, 0);
      }
    }
    if (kt + 1 < NT) STORE(cur ^ 1);
    cur ^= 1;
  }

#pragma unroll
  for (int m = 0; m < 4; ++m) {
    const int rbase = wr * 64 + m * 16 + ((lane >> 4) << 2);
    float wts[4]; bool val[4];
#pragma unroll
    for (int j = 0; j < 4; ++j) {
      int r = m0 + rbase + j;
      val[j] = r < ce;
      wts[j] = val[j] ? lw[e * TK + r] : 0.f;
    }
#pragma unroll
    for (int n = 0; n < 4; ++n) {
      const int col = n0 + wc * 64 + n * 16 + (lane & 15);
#pragma unroll
      for (int j = 0; j < 4; ++j) {
        if (!val[j]) continue;
        float s1 = acc1[m][n][j], s3 = acc3[m][n][j];
        float h = s1 / (1.f + __expf(-s1)) * s3 * wts[j];
        H[(size_t)(base + m0 + rbase + j) * FF + col] = f2bf(h);
      }
    }
  }
}

__global__ __launch_bounds__(256, 2)
void k_gemm2(const unsigned short* __restrict__ H, const float* __restrict__ w2g,
             const int* __restrict__ cnt, const int* __restrict__ off,
             const int* __restrict__ ltok, float* __restrict__ out) {
  const int e = blockIdx.z;
  const int ce = cnt[e];
  const int m0 = blockIdx.y * BM;
  if (m0 >= ce) return;
  const int n0 = blockIdx.x * BN;
  const int tid = threadIdx.x, lane = tid & 63, wv = tid >> 6;
  const int wr = wv >> 1, wc = wv & 1;
  const float* W2 = w2g + (size_t)e * FF * DD;
  const int base = off[e];

  __shared__ unsigned short As[2][BM * BKR];
  __shared__ unsigned short Bs[2][BN * BKR];

  const int arow = tid >> 1, ah = tid & 1;
  const bool aval = (m0 + arow) < ce;
  const unsigned short* hrow = H + (size_t)(base + m0 + arow) * FF;
  const int kblk = tid >> 5, nblk = tid & 31;

  const int kb = (lane >> 4) * 16;
  int aOff[4], bOff[4], wAoff[2], wBoff[4];
#pragma unroll
  for (int m = 0; m < 4; ++m) aOff[m] = swzoff(wr * 64 + m * 16 + (lane & 15), kb);
#pragma unroll
  for (int n = 0; n < 4; ++n) bOff[n] = swzoff(permB(wc * 64 + n * 16 + (lane & 15)), kb);
#pragma unroll
  for (int j = 0; j < 2; ++j) wAoff[j] = swzoff(arow, ah * 32 + j * 16);
#pragma unroll
  for (int j = 0; j < 4; ++j) wBoff[j] = swzoff(permB(nblk * 4 + j), kblk * 8);

  f32x4 acc[4][4];
#pragma unroll
  for (int m = 0; m < 4; ++m)
#pragma unroll
    for (int n = 0; n < 4; ++n)
#pragma unroll
      for (int j = 0; j < 4; ++j) acc[m][n][j] = 0.f;

  bf16x8 av2[2];
  f32x4 wv2[4];

  auto LOAD = [&](int kt) {
    const int k0 = kt * BKR;
#pragma unroll
    for (int j = 0; j < 2; ++j) {
      if (aval) av2[j] = *(const bf16x8*)(hrow + k0 + ah * 16 + j * 8);
      else {
#pragma unroll
        for (int q = 0; q < 8; ++q) av2[j][q] = 0;
      }
    }
    const float* p = W2 + (size_t)(k0 + kblk * 4) * DD + (n0 + nblk * 4);
#pragma unroll
    for (int r = 0; r < 4; ++r) wv2[r] = *(const f32x4*)(p + (size_t)r * DD);
  };
  auto STORE = [&](int buf) {
#pragma unroll
    for (int j = 0; j < 2; ++j) *(bf16x8*)((char*)As[buf] + wAoff[j]) = av2[j];
#pragma unroll
    for (int j = 0; j < 4; ++j) {
      bf16x4 t;
      t[0] = (short)f2bf(wv2[0][j]); t[1] = (short)f2bf(wv2[1][j]);
      t[2] = (short)f2bf(wv2[2][j]); t[3] = (short)f2bf(wv2[3][j]);
      *(bf16x4*)((char*)Bs[buf] + wBoff[j]) = t;
    }
  };

  LOAD(0); STORE(0);
  int cur = 0;
  const int NT = FF / BKR;
  for (int kt = 0; kt < NT; ++kt) {
    if (kt + 1 < NT) LOAD(kt + 1);
    __syncthreads();
    bf16x8 af[4];
#pragma unroll
    for (int m = 0; m < 4; ++m) af[m] = *(const bf16x8*)((const char*)As[cur] + aOff[m]);
#pragma unroll
    for (int n = 0; n < 4; ++n) {
      bf16x8 bf = *(const bf16x8*)((const char*)Bs[cur] + bOff[n]);
#pragma unroll
      for (int m = 0; m < 4; ++m)
        acc[m][n] = __builtin_amdgcn_mfma_f32_16x16x32_bf16(af[m], bf, acc[m][n], 0, 0, 0);
    }
    if (kt + 1 < NT) STORE(cur ^ 1);
    cur ^= 1;
  }

#pragma unroll
  for (int m = 0; m < 4; ++m) {
    const int rbase = wr * 64 + m * 16 + ((lane >> 4) << 2);
    int toks[4]; bool val[4];
#pragma unroll
    for (int j = 0; j < 4; ++j) {
      int r = m0 + rbase + j;
      val[j] = r < ce;
      toks[j] = val[j] ? ltok[e * TK + r] : 0;
    }
#pragma unroll
    for (int n = 0; n < 4; ++n) {
      const int col = n0 + wc * 64 + n * 16 + (lane & 15);
#pragma unroll
      for (int j = 0; j < 4; ++j)
        if (val[j]) atomicAdd(out + (size_t)toks[j] * DD + col, acc[m][n][j]);
    }
  }
}

extern "C" void kernel_launch(void* const* d_in, const int* in_sizes, int n_in,
                              void* d_out, int out_size, void* d_ws, size_t ws_size,
                              hipStream_t stream) {
  const float* x  = (const float*)d_in[0];
  const float* gw = (const float*)d_in[1];
  const float* w1 = (const float*)d_in[2];
  const float* w3 = (const float*)d_in[3];
  const float* w2 = (const float*)d_in[4];
  float* out = (float*)d_out;

  char* ws = (char*)d_ws;
  int*   cnt  = (int*)(ws);
  int*   off  = (int*)(ws + 64);
  int*   ltok = (int*)(ws + 256);
  float* lw   = (float*)(ws + 256 + (size_t)NE * TK * 4);
  int2*  t2s  = (int2*)(ws + 512 * 1024);

  const size_t SZ_XB  = (size_t)TK * DD * 2;         // 16.8 MB
  const size_t SZ_W13 = (size_t)NE * 2 * FF * DD * 2; // 268.4 MB
  const size_t SZ_W   = (size_t)NE * DD * FF * 2;     // 134.2 MB
  const size_t SZ_H   = (size_t)2 * TK * FF * 2;      // 67.1 MB
  size_t o = (size_t)1 << 20;
  unsigned short* xb   = (unsigned short*)(ws + o); o += SZ_XB;
  unsigned short* w13t = (unsigned short*)(ws + o); o += SZ_W13;
  unsigned short* w2t  = (unsigned short*)(ws + o); o += SZ_W;
  unsigned short* Hg   = (unsigned short*)(ws + o); o += SZ_H;
  unsigned short* O    = w13t;  // dead after k_gemm1p; slot-output aliases it
  const bool full = (ws_size >= o);

  hipMemsetAsync(cnt, 0, 64, stream);

  if (full) {
    k_router<<<dim3(TK / 4), 256, 0, stream>>>(x, gw, cnt, ltok, lw, xb, t2s);
    k_prefix<<<dim3(1), 64, 0, stream>>>(cnt, off);
    k_tr<<<dim3(FF / 32, DD / 256, NE), 256, 0, stream>>>(w1, w13t, DD, FF, 1);
    k_tr<<<dim3(FF / 32, DD / 256, NE), 256, 0, stream>>>(w3, w13t, DD, FF, 2);
    k_tr<<<dim3(DD / 32, FF / 256, NE), 256, 0, stream>>>(w2, w2t, FF, DD, 0);
    k_gemm1p<<<dim3(2 * FF / 256, TK / 256, NE), 512, 0, stream>>>(xb, w13t, cnt, off, ltok, lw, Hg);
    k_gemm2g<<<dim3(DD / BN2, TK / BM, NE), 256, 0, stream>>>(Hg, w2t, cnt, off, O);
    k_comb<<<dim3(TK * DD / 8 / 256), 256, 0, stream>>>(O, t2s, off, out);
  } else {
    unsigned short* H = (unsigned short*)(ws + ((size_t)1 << 20));
    if (ws_size < ((size_t)1 << 20) + SZ_H) return;
    hipMemsetAsync(d_out, 0, (size_t)out_size * 4, stream);
    k_router<<<dim3(TK / 4), 256, 0, stream>>>(x, gw, cnt, ltok, lw,
                                               (unsigned short*)nullptr, (int2*)nullptr);
    k_prefix<<<dim3(1), 64, 0, stream>>>(cnt, off);
    k_gemm1<<<dim3(FF / BN, TK / BM, NE), 256, 0, stream>>>(x, w1, w3, cnt, off, ltok, lw, H);
    k_gemm2<<<dim3(DD / BN, TK / BM, NE), 256, 0, stream>>>(H, w2, cnt, off, ltok, out);
  }
}

// Round 11
// 919.615 us; speedup vs baseline: 1.0864x; 1.0864x over previous
//
#include <hip/hip_runtime.h>
#include <hip/hip_bf16.h>

#define TK 4096   // tokens
#define DD 2048   // hidden
#define FF 4096   // intermediate
#define NE 8      // experts
#define BM 128
#define BN 128
#define BKR 32    // reg-staged fallback K-tile
#define BKP 64    // pipelined K-tile (asymmetric dbuf)

typedef __attribute__((ext_vector_type(8))) short bf16x8;
typedef __attribute__((ext_vector_type(4))) short bf16x4;
typedef __attribute__((ext_vector_type(4))) float f32x4;

__device__ __forceinline__ unsigned short f2bf(float f) {
  return __builtin_bit_cast(unsigned short, __float2bfloat16(f));  // v_cvt_pk_bf16_f32
}
__device__ __forceinline__ float bf2f(unsigned short u) {
  return __builtin_bit_cast(float, (unsigned)u << 16);
}

// async global->LDS, 16B per lane. LDS dest is wave-uniform base + lane*16.
__device__ __forceinline__ void gl16(const unsigned short* g, unsigned short* l) {
  __builtin_amdgcn_global_load_lds(
      (const __attribute__((address_space(1))) unsigned int*)g,
      (__attribute__((address_space(3))) unsigned int*)l, 16, 0, 0);
}

#define VMCNT(n) asm volatile("s_waitcnt vmcnt(" #n ")" ::: "memory")
#define SBAR()   __builtin_amdgcn_s_barrier()

// ---- fallback-path swizzle helpers ----
__device__ __forceinline__ int g_swz(int row) { return ((row >> 1) & 3) ^ ((row >> 3) & 3); }
__device__ __forceinline__ int swzoff(int row, int bir) {
  return row * 64 + ((((bir >> 4) ^ g_swz(row)) & 3) << 4) + (bir & 15);
}
__device__ __forceinline__ int permB(int f) {
  return (f & 0x60) | ((f & 3) << 3) | ((f >> 2) & 7);
}

// ---------------- router: 1 wave per token (emits X bf16 + token->slot map) ----------------
__global__ void k_router(const float* __restrict__ x, const float* __restrict__ gw,
                         int* __restrict__ cnt, int* __restrict__ ltok,
                         float* __restrict__ lw, unsigned short* __restrict__ xb,
                         int2* __restrict__ t2s) {
  int tok = (blockIdx.x * blockDim.x + threadIdx.x) >> 6;
  int lane = threadIdx.x & 63;
  if (tok >= TK) return;
  const float* xr = x + (size_t)tok * DD;
  float a0=0,a1=0,a2=0,a3=0,a4=0,a5=0,a6=0,a7=0;
  for (int p = 0; p < DD / 256; ++p) {
    int d0 = p * 256 + lane * 4;
    f32x4 xv = *(const f32x4*)(xr + d0);
    if (xb) {
      bf16x4 t;
      t[0] = (short)f2bf(xv[0]); t[1] = (short)f2bf(xv[1]);
      t[2] = (short)f2bf(xv[2]); t[3] = (short)f2bf(xv[3]);
      *(bf16x4*)(xb + (size_t)tok * DD + d0) = t;
    }
#pragma unroll
    for (int j = 0; j < 4; ++j) {
      float xs = xv[j];
      const f32x4* g = (const f32x4*)(gw + (size_t)(d0 + j) * NE);
      f32x4 g0 = g[0], g1 = g[1];
      a0 += xs * g0[0]; a1 += xs * g0[1]; a2 += xs * g0[2]; a3 += xs * g0[3];
      a4 += xs * g1[0]; a5 += xs * g1[1]; a6 += xs * g1[2]; a7 += xs * g1[3];
    }
  }
#pragma unroll
  for (int s = 32; s > 0; s >>= 1) {
    a0 += __shfl_xor(a0, s, 64); a1 += __shfl_xor(a1, s, 64);
    a2 += __shfl_xor(a2, s, 64); a3 += __shfl_xor(a3, s, 64);
    a4 += __shfl_xor(a4, s, 64); a5 += __shfl_xor(a5, s, 64);
    a6 += __shfl_xor(a6, s, 64); a7 += __shfl_xor(a7, s, 64);
  }
  if (lane == 0) {
    float p_[NE] = {a0, a1, a2, a3, a4, a5, a6, a7};
    float m = p_[0];
#pragma unroll
    for (int e = 1; e < NE; ++e) m = fmaxf(m, p_[e]);
    float ssum = 0.f;
#pragma unroll
    for (int e = 0; e < NE; ++e) { p_[e] = __expf(p_[e] - m); ssum += p_[e]; }
    float inv = 1.f / ssum;
    int i1 = 0; float b1 = p_[0];
#pragma unroll
    for (int e = 1; e < NE; ++e) if (p_[e] > b1) { b1 = p_[e]; i1 = e; }
    int i2 = -1; float b2 = -1.f;
#pragma unroll
    for (int e = 0; e < NE; ++e) if (e != i1 && p_[e] > b2) { b2 = p_[e]; i2 = e; }
    int s1 = atomicAdd(&cnt[i1], 1);
    ltok[i1 * TK + s1] = tok; lw[i1 * TK + s1] = b1 * inv;
    int s2 = atomicAdd(&cnt[i2], 1);
    ltok[i2 * TK + s2] = tok; lw[i2 * TK + s2] = b2 * inv;
    if (t2s) t2s[tok] = make_int2(i1 * TK + s1, i2 * TK + s2);
  }
}

__global__ void k_prefix(const int* __restrict__ cnt, int* __restrict__ off) {
  if (threadIdx.x == 0) {
    int a = 0;
#pragma unroll
    for (int e = 0; e < NE; ++e) { off[e] = a; a += cnt[e]; }
    off[NE] = a;
  }
}

// ------- transpose+convert, pure-register: fp32 [R][C] -> bf16 [C][R] -------
__global__ __launch_bounds__(256)
void k_tr(const float* __restrict__ src0, unsigned short* __restrict__ dst0,
          int R, int C) {
  const int e = blockIdx.z;
  const float* src = src0 + (size_t)e * R * C;
  unsigned short* dst = dst0 + (size_t)e * R * C;
  const int tid = threadIdx.x;
  const int w = tid >> 6, lane = tid & 63;
  const int r0 = blockIdx.y * 256 + w * 64 + (lane >> 3) * 8;
  const int c0 = blockIdx.x * 32 + (lane & 7) * 4;
  f32x4 v[8];
#pragma unroll
  for (int j = 0; j < 8; ++j) v[j] = *(const f32x4*)(src + (size_t)(r0 + j) * C + c0);
#pragma unroll
  for (int jc = 0; jc < 4; ++jc) {
    bf16x8 o;
#pragma unroll
    for (int j = 0; j < 8; ++j) o[j] = (short)f2bf(v[j][jc]);
    *(bf16x8*)(dst + (size_t)(c0 + jc) * R + r0) = o;
  }
}

// same, for w1 AND w3 in one launch (z in [0, 2*NE))
__global__ __launch_bounds__(256)
void k_tr13(const float* __restrict__ w1, const float* __restrict__ w3,
            unsigned short* __restrict__ d1, unsigned short* __restrict__ d3) {
  const int z = blockIdx.z;
  const int e = z & (NE - 1);
  const float* src = (z < NE ? w1 : w3) + (size_t)e * DD * FF;
  unsigned short* dst = (z < NE ? d1 : d3) + (size_t)e * DD * FF;
  const int tid = threadIdx.x;
  const int w = tid >> 6, lane = tid & 63;
  const int r0 = blockIdx.y * 256 + w * 64 + (lane >> 3) * 8;
  const int c0 = blockIdx.x * 32 + (lane & 7) * 4;
  f32x4 v[8];
#pragma unroll
  for (int j = 0; j < 8; ++j) v[j] = *(const f32x4*)(src + (size_t)(r0 + j) * FF + c0);
#pragma unroll
  for (int jc = 0; jc < 4; ++jc) {
    bf16x8 o;
#pragma unroll
    for (int j = 0; j < 8; ++j) o[j] = (short)f2bf(v[j][jc]);
    *(bf16x8*)(dst + (size_t)(c0 + jc) * DD + r0) = o;
  }
}

// ---------------- combine: out[t] = O[slot1(t)] + O[slot2(t)] ----------------
__global__ __launch_bounds__(256)
void k_comb(const unsigned short* __restrict__ O, const int2* __restrict__ t2s,
            const int* __restrict__ off, float* __restrict__ out) {
  const int idx = blockIdx.x * 256 + threadIdx.x;
  const int t = idx >> 8;
  const int d0 = (idx & 255) * 8;
  const int2 v = t2s[t];
  const int s1 = off[v.x >> 12] + (v.x & (TK - 1));
  const int s2 = off[v.y >> 12] + (v.y & (TK - 1));
  bf16x8 a = *(const bf16x8*)(O + (size_t)s1 * DD + d0);
  bf16x8 b = *(const bf16x8*)(O + (size_t)s2 * DD + d0);
  f32x4 r0, r1;
#pragma unroll
  for (int j = 0; j < 4; ++j) {
    r0[j] = bf2f((unsigned short)a[j]) + bf2f((unsigned short)b[j]);
    r1[j] = bf2f((unsigned short)a[j + 4]) + bf2f((unsigned short)b[j + 4]);
  }
  float* o = out + (size_t)t * DD + d0;
  *(f32x4*)o = r0;
  *(f32x4*)(o + 4) = r1;
}

// ============ pipelined GEMMs: BK=64, asymmetric double-buffer (r8 winner) ============
// LDS tile [rows][64 bf16] = 128B rows, 8x16B chunks; chunk swizzle c^=(r&7)
// on SOURCE addr (gl16 dest linear) and on frag read (both-sides, rule #21).
// Steady loop: STAGE_B(t+1) -> vmcnt(N) -> s_barrier -> COMPUTE(t) -> s_barrier
// -> STAGE_A(t+1). B(t+1)'s loads stay in flight across a full compute phase.

// ---------------- GEMM1: H = silu(X W1) * (X W3) * w ----------------
// LDS 80 KB: As 16K + B1s 2x16K + B3s 2x16K -> exactly 2 blocks/CU.
// (256,2) load-bearing: acc1+acc3 = 128 regs/thread (round-3 spill lesson).
__global__ __launch_bounds__(256, 2)
void k_gemm1g(const unsigned short* __restrict__ xb, const unsigned short* __restrict__ w1t,
              const unsigned short* __restrict__ w3t, const int* __restrict__ cnt,
              const int* __restrict__ off, const int* __restrict__ ltok,
              const float* __restrict__ lw, unsigned short* __restrict__ H) {
  const int e = blockIdx.z;
  const int ce = cnt[e];
  const int m0 = blockIdx.y * BM;
  if (m0 >= ce) return;
  const int n0 = blockIdx.x * BN;
  const int tid = threadIdx.x, lane = tid & 63, w = tid >> 6;
  const int wr = w >> 1, wc = w & 1;
  const unsigned short* W1 = w1t + (size_t)e * FF * DD;  // [F][D]
  const unsigned short* W3 = w3t + (size_t)e * FF * DD;
  const int base = off[e];

  __shared__ __align__(16) unsigned short As[BM * BKP];        // 16 KB single
  __shared__ __align__(16) unsigned short B1s[2][BM * BKP];    // 32 KB dbuf
  __shared__ __align__(16) unsigned short B3s[2][BM * BKP];    // 32 KB dbuf

  const int swz8 = ((lane & 7) ^ ((lane >> 3) & 7)) * 8;
  const unsigned short *aSrc[4], *b1Src[4], *b3Src[4];
#pragma unroll
  for (int i = 0; i < 4; ++i) {
    int row = w * 32 + i * 8 + (lane >> 3);
    int gm = m0 + row;
    int tok = (gm < ce) ? ltok[e * TK + gm] : ltok[e * TK];  // clamp; masked at store
    aSrc[i]  = xb + (size_t)tok * DD + swz8;
    b1Src[i] = W1 + (size_t)(n0 + row) * DD + swz8;
    b3Src[i] = W3 + (size_t)(n0 + row) * DD + swz8;
  }

  const int kc = lane >> 4;
  int aOff[4][2], bOff[4][2];
#pragma unroll
  for (int m = 0; m < 4; ++m) {
    int row = wr * 64 + m * 16 + (lane & 15);
#pragma unroll
    for (int kk = 0; kk < 2; ++kk) {
      int c = kk * 4 + kc;
      aOff[m][kk] = row * 128 + ((c ^ (row & 7)) << 4);
    }
  }
#pragma unroll
  for (int n = 0; n < 4; ++n) {
    int row = wc * 64 + n * 16 + (lane & 15);
#pragma unroll
    for (int kk = 0; kk < 2; ++kk) {
      int c = kk * 4 + kc;
      bOff[n][kk] = row * 128 + ((c ^ (row & 7)) << 4);
    }
  }

  f32x4 acc1[4][4], acc3[4][4];
#pragma unroll
  for (int m = 0; m < 4; ++m)
#pragma unroll
    for (int n = 0; n < 4; ++n)
#pragma unroll
      for (int j = 0; j < 4; ++j) { acc1[m][n][j] = 0.f; acc3[m][n][j] = 0.f; }

  auto STAGE_A = [&]() {   // 4 gl16/wave
#pragma unroll
    for (int i = 0; i < 4; ++i) {
      gl16(aSrc[i], &As[(w * 4 + i) * 512]);
      aSrc[i] += BKP;
    }
  };
  auto STAGE_B = [&](int buf) {   // 8 gl16/wave
#pragma unroll
    for (int i = 0; i < 4; ++i) {
      const int seg = w * 4 + i;
      gl16(b1Src[i], &B1s[buf][seg * 512]);
      gl16(b3Src[i], &B3s[buf][seg * 512]);
      b1Src[i] += BKP; b3Src[i] += BKP;
    }
  };
  auto COMPUTE = [&](int buf) {
#pragma unroll
    for (int kk = 0; kk < 2; ++kk) {
      bf16x8 af[4];
#pragma unroll
      for (int m = 0; m < 4; ++m) af[m] = *(const bf16x8*)((const char*)As + aOff[m][kk]);
#pragma unroll
      for (int n = 0; n < 4; ++n) {
        bf16x8 b1 = *(const bf16x8*)((const char*)B1s[buf] + bOff[n][kk]);
        bf16x8 b3 = *(const bf16x8*)((const char*)B3s[buf] + bOff[n][kk]);
#pragma unroll
        for (int m = 0; m < 4; ++m) {
          acc1[m][n] = __builtin_amdgcn_mfma_f32_16x16x32_bf16(af[m], b1, acc1[m][n], 0, 0, 0);
          acc3[m][n] = __builtin_amdgcn_mfma_f32_16x16x32_bf16(af[m], b3, acc3[m][n], 0, 0, 0);
        }
      }
    }
  };

  const int NT = DD / BKP;  // 32
  STAGE_A();
  STAGE_B(0);
  int b = 0;
  for (int kt = 0; kt < NT - 1; ++kt) {
    STAGE_B(b ^ 1);   // tile kt+1's B: flies across both barriers + compute
    VMCNT(8);         // A(kt)+B(kt) complete; B(kt+1)'s 8 stay in flight
    SBAR();
    COMPUTE(b);
    SBAR();           // all waves done reading As before restage
    STAGE_A();        // tile kt+1's A (single buffer; L2-hot, short exposure)
    b ^= 1;
  }
  VMCNT(0);
  SBAR();
  COMPUTE(b);

#pragma unroll
  for (int m = 0; m < 4; ++m) {
    const int rbase = wr * 64 + m * 16 + ((lane >> 4) << 2);
    float wts[4]; bool val[4];
#pragma unroll
    for (int j = 0; j < 4; ++j) {
      int r = m0 + rbase + j;
      val[j] = r < ce;
      wts[j] = val[j] ? lw[e * TK + r] : 0.f;
    }
#pragma unroll
    for (int n = 0; n < 4; ++n) {
      const int col = n0 + wc * 64 + n * 16 + (lane & 15);
#pragma unroll
      for (int j = 0; j < 4; ++j) {
        if (!val[j]) continue;
        float s1 = acc1[m][n][j], s3 = acc3[m][n][j];
        float h = s1 / (1.f + __expf(-s1)) * s3 * wts[j];
        H[(size_t)(base + m0 + rbase + j) * FF + col] = f2bf(h);
      }
    }
  }
}

// ---------------- GEMM2: O[slot] = H W2t (bf16 slot-output, no atomics) ----------------
// r8 structure: LDS 48 KB (As 16K single + Bs 2x16K dbuf), (256,3) = 12 waves/CU.
__global__ __launch_bounds__(256, 3)
void k_gemm2g(const unsigned short* __restrict__ H, const unsigned short* __restrict__ w2t,
              const int* __restrict__ cnt, const int* __restrict__ off,
              unsigned short* __restrict__ O) {
  const int e = blockIdx.z;
  const int ce = cnt[e];
  const int m0 = blockIdx.y * BM;
  if (m0 >= ce) return;
  const int n0 = blockIdx.x * BN;
  const int tid = threadIdx.x, lane = tid & 63, w = tid >> 6;
  const int wr = w >> 1, wc = w & 1;
  const unsigned short* W2 = w2t + (size_t)e * DD * FF;  // [D][F]
  const int base = off[e];

  __shared__ __align__(16) unsigned short As[BM * BKP];
  __shared__ __align__(16) unsigned short Bs[2][BN * BKP];

  const int swz8 = ((lane & 7) ^ ((lane >> 3) & 7)) * 8;
  const unsigned short *aSrc[4], *bSrc[4];
#pragma unroll
  for (int i = 0; i < 4; ++i) {
    int row = w * 32 + i * 8 + (lane >> 3);
    int gm = m0 + row;
    int hr = (gm < ce) ? gm : 0;
    aSrc[i] = H + (size_t)(base + hr) * FF + swz8;
    bSrc[i] = W2 + (size_t)(n0 + row) * FF + swz8;
  }

  const int kc = lane >> 4;
  int aOff[4][2], bOff[4][2];
#pragma unroll
  for (int m = 0; m < 4; ++m) {
    int row = wr * 64 + m * 16 + (lane & 15);
#pragma unroll
    for (int kk = 0; kk < 2; ++kk) {
      int c = kk * 4 + kc;
      aOff[m][kk] = row * 128 + ((c ^ (row & 7)) << 4);
    }
  }
#pragma unroll
  for (int n = 0; n < 4; ++n) {
    int row = wc * 64 + n * 16 + (lane & 15);
#pragma unroll
    for (int kk = 0; kk < 2; ++kk) {
      int c = kk * 4 + kc;
      bOff[n][kk] = row * 128 + ((c ^ (row & 7)) << 4);
    }
  }

  f32x4 acc[4][4];
#pragma unroll
  for (int m = 0; m < 4; ++m)
#pragma unroll
    for (int n = 0; n < 4; ++n)
#pragma unroll
      for (int j = 0; j < 4; ++j) acc[m][n][j] = 0.f;

  auto STAGE_A = [&]() {
#pragma unroll
    for (int i = 0; i < 4; ++i) {
      gl16(aSrc[i], &As[(w * 4 + i) * 512]);
      aSrc[i] += BKP;
    }
  };
  auto STAGE_B = [&](int buf) {
#pragma unroll
    for (int i = 0; i < 4; ++i) {
      gl16(bSrc[i], &Bs[buf][(w * 4 + i) * 512]);
      bSrc[i] += BKP;
    }
  };
  auto COMPUTE = [&](int buf) {
#pragma unroll
    for (int kk = 0; kk < 2; ++kk) {
      bf16x8 af[4];
#pragma unroll
      for (int m = 0; m < 4; ++m) af[m] = *(const bf16x8*)((const char*)As + aOff[m][kk]);
#pragma unroll
      for (int n = 0; n < 4; ++n) {
        bf16x8 bf = *(const bf16x8*)((const char*)Bs[buf] + bOff[n][kk]);
#pragma unroll
        for (int m = 0; m < 4; ++m)
          acc[m][n] = __builtin_amdgcn_mfma_f32_16x16x32_bf16(af[m], bf, acc[m][n], 0, 0, 0);
      }
    }
  };

  const int NT = FF / BKP;  // 64
  STAGE_A();
  STAGE_B(0);
  int b = 0;
  for (int kt = 0; kt < NT - 1; ++kt) {
    STAGE_B(b ^ 1);
    VMCNT(4);        // A(kt)+B(kt) done; B(kt+1)'s 4 in flight
    SBAR();
    COMPUTE(b);
    SBAR();
    STAGE_A();
    b ^= 1;
  }
  VMCNT(0);
  SBAR();
  COMPUTE(b);

#pragma unroll
  for (int m = 0; m < 4; ++m) {
    const int rbase = wr * 64 + m * 16 + ((lane >> 4) << 2);
#pragma unroll
    for (int n = 0; n < 4; ++n) {
      const int col = n0 + wc * 64 + n * 16 + (lane & 15);
#pragma unroll
      for (int j = 0; j < 4; ++j) {
        int r = m0 + rbase + j;
        if (r < ce) O[(size_t)(base + r) * DD + col] = f2bf(acc[m][n][j]);
      }
    }
  }
}

// ================== fallback reg-staged GEMMs (used only if ws too small) ==================
__global__ __launch_bounds__(256, 2)
void k_gemm1(const float* __restrict__ x, const float* __restrict__ w1g,
             const float* __restrict__ w3g, const int* __restrict__ cnt,
             const int* __restrict__ off, const int* __restrict__ ltok,
             const float* __restrict__ lw, unsigned short* __restrict__ H) {
  const int e = blockIdx.z;
  const int ce = cnt[e];
  const int m0 = blockIdx.y * BM;
  if (m0 >= ce) return;
  const int n0 = blockIdx.x * BN;
  const int tid = threadIdx.x, lane = tid & 63, wv = tid >> 6;
  const int wr = wv >> 1, wc = wv & 1;
  const float* W1 = w1g + (size_t)e * DD * FF;
  const float* W3 = w3g + (size_t)e * DD * FF;
  const int base = off[e];

  __shared__ unsigned short As[2][BM * BKR];
  __shared__ unsigned short B1s[2][BN * BKR];
  __shared__ unsigned short B3s[2][BN * BKR];

  const int arow = tid >> 1, ah = tid & 1;
  const float* xrow = (m0 + arow < ce) ? (x + (size_t)ltok[e * TK + (m0 + arow)] * DD) : nullptr;
  const int dblk = tid >> 5, fblk = tid & 31;

  const int kb = (lane >> 4) * 16;
  int aOff[4], bOff[4], wAoff[4], wBoff[4];
#pragma unroll
  for (int m = 0; m < 4; ++m) aOff[m] = swzoff(wr * 64 + m * 16 + (lane & 15), kb);
#pragma unroll
  for (int n = 0; n < 4; ++n) bOff[n] = swzoff(permB(wc * 64 + n * 16 + (lane & 15)), kb);
#pragma unroll
  for (int j = 0; j < 4; ++j) {
    wAoff[j] = swzoff(arow, ah * 32 + j * 8);
    wBoff[j] = swzoff(permB(fblk * 4 + j), dblk * 8);
  }

  f32x4 acc1[4][4], acc3[4][4];
#pragma unroll
  for (int m = 0; m < 4; ++m)
#pragma unroll
    for (int n = 0; n < 4; ++n)
#pragma unroll
      for (int j = 0; j < 4; ++j) { acc1[m][n][j] = 0.f; acc3[m][n][j] = 0.f; }

  f32x4 av[4], v1[4], v3[4];

  auto LOAD = [&](int kt) {
    const int k0 = kt * BKR;
#pragma unroll
    for (int j = 0; j < 4; ++j) {
      if (xrow) av[j] = *(const f32x4*)(xrow + k0 + ah * 16 + j * 4);
      else { av[j][0] = 0.f; av[j][1] = 0.f; av[j][2] = 0.f; av[j][3] = 0.f; }
    }
    const float* p1 = W1 + (size_t)(k0 + dblk * 4) * FF + (n0 + fblk * 4);
    const float* p3 = W3 + (size_t)(k0 + dblk * 4) * FF + (n0 + fblk * 4);
#pragma unroll
    for (int r = 0; r < 4; ++r) {
      v1[r] = *(const f32x4*)(p1 + (size_t)r * FF);
      v3[r] = *(const f32x4*)(p3 + (size_t)r * FF);
    }
  };
  auto STORE = [&](int buf) {
#pragma unroll
    for (int j = 0; j < 4; ++j) {
      bf16x4 t;
      t[0] = (short)f2bf(av[j][0]); t[1] = (short)f2bf(av[j][1]);
      t[2] = (short)f2bf(av[j][2]); t[3] = (short)f2bf(av[j][3]);
      *(bf16x4*)((char*)As[buf] + wAoff[j]) = t;
    }
#pragma unroll
    for (int j = 0; j < 4; ++j) {
      bf16x4 t1, t3;
      t1[0] = (short)f2bf(v1[0][j]); t1[1] = (short)f2bf(v1[1][j]);
      t1[2] = (short)f2bf(v1[2][j]); t1[3] = (short)f2bf(v1[3][j]);
      t3[0] = (short)f2bf(v3[0][j]); t3[1] = (short)f2bf(v3[1][j]);
      t3[2] = (short)f2bf(v3[2][j]); t3[3] = (short)f2bf(v3[3][j]);
      *(bf16x4*)((char*)B1s[buf] + wBoff[j]) = t1;
      *(bf16x4*)((char*)B3s[buf] + wBoff[j]) = t3;
    }
  };

  LOAD(0); STORE(0);
  int cur = 0;
  const int NT = DD / BKR;
  for (int kt = 0; kt < NT; ++kt) {
    if (kt + 1 < NT) LOAD(kt + 1);
    __syncthreads();
    bf16x8 af[4];
#pragma unroll
    for (int m = 0; m < 4; ++m) af[m] = *(const bf16x8*)((const char*)As[cur] + aOff[m]);
#pragma unroll
    for (int n = 0; n < 4; ++n) {
      bf16x8 b1 = *(const bf16x8*)((const char*)B1s[cur] + bOff[n]);
      bf16x8 b3 = *(const bf16x8*)((const char*)B3s[cur] + bOff[n]);
#pragma unroll
      for (int m = 0; m < 4; ++m) {
        acc1[m][n] = __builtin_amdgcn_mfma_f32_16x16x32_bf16(af[m], b1, acc1[m][n], 0, 0, 0);
        acc3[m][n] = __builtin_amdgcn_mfma_f32_16x16x32_bf16(af[m], b3, acc3[m][n], 0, 0, 0);
      }
    }
    if (kt + 1 < NT) STORE(cur ^ 1);
    cur ^= 1;
  }

#pragma unroll
  for (int m = 0; m < 4; ++m) {
    const int rbase = wr * 64 + m * 16 + ((lane >> 4) << 2);
    float wts[4]; bool val[4];
#pragma unroll
    for (int j = 0; j < 4; ++j) {
      int r = m0 + rbase + j;
      val[j] = r < ce;
      wts[j] = val[j] ? lw[e * TK + r] : 0.f;
    }
#pragma unroll
    for (int n = 0; n < 4; ++n) {
      const int col = n0 + wc * 64 + n * 16 + (lane & 15);
#pragma unroll
      for (int j = 0; j < 4; ++j) {
        if (!val[j]) continue;
        float s1 = acc1[m][n][j], s3 = acc3[m][n][j];
        float h = s1 / (1.f + __expf(-s1)) * s3 * wts[j];
        H[(size_t)(base + m0 + rbase + j) * FF + col] = f2bf(h);
      }
    }
  }
}

__global__ __launch_bounds__(256, 2)
void k_gemm2(const unsigned short* __restrict__ H, const float* __restrict__ w2g,
             const int* __restrict__ cnt, const int* __restrict__ off,
             const int* __restrict__ ltok, float* __restrict__ out) {
  const int e = blockIdx.z;
  const int ce = cnt[e];
  const int m0 = blockIdx.y * BM;
  if (m0 >= ce) return;
  const int n0 = blockIdx.x * BN;
  const int tid = threadIdx.x, lane = tid & 63, wv = tid >> 6;
  const int wr = wv >> 1, wc = wv & 1;
  const float* W2 = w2g + (size_t)e * FF * DD;
  const int base = off[e];

  __shared__ unsigned short As[2][BM * BKR];
  __shared__ unsigned short Bs[2][BN * BKR];

  const int arow = tid >> 1, ah = tid & 1;
  const bool aval = (m0 + arow) < ce;
  const unsigned short* hrow = H + (size_t)(base + m0 + arow) * FF;
  const int kblk = tid >> 5, nblk = tid & 31;

  const int kb = (lane >> 4) * 16;
  int aOff[4], bOff[4], wAoff[2], wBoff[4];
#pragma unroll
  for (int m = 0; m < 4; ++m) aOff[m] = swzoff(wr * 64 + m * 16 + (lane & 15), kb);
#pragma unroll
  for (int n = 0; n < 4; ++n) bOff[n] = swzoff(permB(wc * 64 + n * 16 + (lane & 15)), kb);
#pragma unroll
  for (int j = 0; j < 2; ++j) wAoff[j] = swzoff(arow, ah * 32 + j * 16);
#pragma unroll
  for (int j = 0; j < 4; ++j) wBoff[j] = swzoff(permB(nblk * 4 + j), kblk * 8);

  f32x4 acc[4][4];
#pragma unroll
  for (int m = 0; m < 4; ++m)
#pragma unroll
    for (int n = 0; n < 4; ++n)
#pragma unroll
      for (int j = 0; j < 4; ++j) acc[m][n][j] = 0.f;

  bf16x8 av2[2];
  f32x4 wv2[4];

  auto LOAD = [&](int kt) {
    const int k0 = kt * BKR;
#pragma unroll
    for (int j = 0; j < 2; ++j) {
      if (aval) av2[j] = *(const bf16x8*)(hrow + k0 + ah * 16 + j * 8);
      else {
#pragma unroll
        for (int q = 0; q < 8; ++q) av2[j][q] = 0;
      }
    }
    const float* p = W2 + (size_t)(k0 + kblk * 4) * DD + (n0 + nblk * 4);
#pragma unroll
    for (int r = 0; r < 4; ++r) wv2[r] = *(const f32x4*)(p + (size_t)r * DD);
  };
  auto STORE = [&](int buf) {
#pragma unroll
    for (int j = 0; j < 2; ++j) *(bf16x8*)((char*)As[buf] + wAoff[j]) = av2[j];
#pragma unroll
    for (int j = 0; j < 4; ++j) {
      bf16x4 t;
      t[0] = (short)f2bf(wv2[0][j]); t[1] = (short)f2bf(wv2[1][j]);
      t[2] = (short)f2bf(wv2[2][j]); t[3] = (short)f2bf(wv2[3][j]);
      *(bf16x4*)((char*)Bs[buf] + wBoff[j]) = t;
    }
  };

  LOAD(0); STORE(0);
  int cur = 0;
  const int NT = FF / BKR;
  for (int kt = 0; kt < NT; ++kt) {
    if (kt + 1 < NT) LOAD(kt + 1);
    __syncthreads();
    bf16x8 af[4];
#pragma unroll
    for (int m = 0; m < 4; ++m) af[m] = *(const bf16x8*)((const char*)As[cur] + aOff[m]);
#pragma unroll
    for (int n = 0; n < 4; ++n) {
      bf16x8 bf = *(const bf16x8*)((const char*)Bs[cur] + bOff[n]);
#pragma unroll
      for (int m = 0; m < 4; ++m)
        acc[m][n] = __builtin_amdgcn_mfma_f32_16x16x32_bf16(af[m], bf, acc[m][n], 0, 0, 0);
    }
    if (kt + 1 < NT) STORE(cur ^ 1);
    cur ^= 1;
  }

#pragma unroll
  for (int m = 0; m < 4; ++m) {
    const int rbase = wr * 64 + m * 16 + ((lane >> 4) << 2);
    int toks[4]; bool val[4];
#pragma unroll
    for (int j = 0; j < 4; ++j) {
      int r = m0 + rbase + j;
      val[j] = r < ce;
      toks[j] = val[j] ? ltok[e * TK + r] : 0;
    }
#pragma unroll
    for (int n = 0; n < 4; ++n) {
      const int col = n0 + wc * 64 + n * 16 + (lane & 15);
#pragma unroll
      for (int j = 0; j < 4; ++j)
        if (val[j]) atomicAdd(out + (size_t)toks[j] * DD + col, acc[m][n][j]);
    }
  }
}

extern "C" void kernel_launch(void* const* d_in, const int* in_sizes, int n_in,
                              void* d_out, int out_size, void* d_ws, size_t ws_size,
                              hipStream_t stream) {
  const float* x  = (const float*)d_in[0];
  const float* gw = (const float*)d_in[1];
  const float* w1 = (const float*)d_in[2];
  const float* w3 = (const float*)d_in[3];
  const float* w2 = (const float*)d_in[4];
  float* out = (float*)d_out;

  char* ws = (char*)d_ws;
  int*   cnt  = (int*)(ws);
  int*   off  = (int*)(ws + 64);
  int*   ltok = (int*)(ws + 256);
  float* lw   = (float*)(ws + 256 + (size_t)NE * TK * 4);
  int2*  t2s  = (int2*)(ws + 512 * 1024);

  const size_t SZ_XB = (size_t)TK * DD * 2;        // 16.8 MB
  const size_t SZ_W  = (size_t)NE * DD * FF * 2;   // 134.2 MB
  const size_t SZ_H  = (size_t)2 * TK * FF * 2;    // 67.1 MB
  size_t o = (size_t)1 << 20;
  unsigned short* xb  = (unsigned short*)(ws + o); o += SZ_XB;
  unsigned short* w1t = (unsigned short*)(ws + o); o += SZ_W;
  unsigned short* w3t = (unsigned short*)(ws + o); o += SZ_W;
  unsigned short* w2t = (unsigned short*)(ws + o); o += SZ_W;
  unsigned short* Hg  = (unsigned short*)(ws + o); o += SZ_H;
  unsigned short* O   = w1t;  // dead after k_gemm1g; 33.6 MB slot-output aliases it
  const bool full = (ws_size >= o);

  hipMemsetAsync(cnt, 0, 64, stream);

  if (full) {
    k_router<<<dim3(TK / 4), 256, 0, stream>>>(x, gw, cnt, ltok, lw, xb, t2s);
    k_prefix<<<dim3(1), 64, 0, stream>>>(cnt, off);
    k_tr13<<<dim3(FF / 32, DD / 256, 2 * NE), 256, 0, stream>>>(w1, w3, w1t, w3t);
    k_tr<<<dim3(DD / 32, FF / 256, NE), 256, 0, stream>>>(w2, w2t, FF, DD);
    k_gemm1g<<<dim3(FF / BN, TK / BM, NE), 256, 0, stream>>>(xb, w1t, w3t, cnt, off, ltok, lw, Hg);
    k_gemm2g<<<dim3(DD / BN, TK / BM, NE), 256, 0, stream>>>(Hg, w2t, cnt, off, O);
    k_comb<<<dim3(TK * DD / 8 / 256), 256, 0, stream>>>(O, t2s, off, out);
  } else {
    unsigned short* H = (unsigned short*)(ws + ((size_t)1 << 20));
    if (ws_size < ((size_t)1 << 20) + SZ_H) return;
    hipMemsetAsync(d_out, 0, (size_t)out_size * 4, stream);
    k_router<<<dim3(TK / 4), 256, 0, stream>>>(x, gw, cnt, ltok, lw,
                                               (unsigned short*)nullptr, (int2*)nullptr);
    k_prefix<<<dim3(1), 64, 0, stream>>>(cnt, off);
    k_gemm1<<<dim3(FF / BN, TK / BM, NE), 256, 0, stream>>>(x, w1, w3, cnt, off, ltok, lw, H);
    k_gemm2<<<dim3(DD / BN, TK / BM, NE), 256, 0, stream>>>(H, w2, cnt, off, ltok, out);
  }
}